// Round 7
// baseline (348.080 us; speedup 1.0000x reference)
//
#include <hip/hip_runtime.h>
#include <hip/hip_bf16.h>

// Problem constants
#define BATCH  128
#define HWN    196          // (224/16)^2 patches per sample
#define HIDN   768
#define KN     768          // 3*16*16
#define IMGSZ  224
#define IMG2   (224*224)
#define MTOT   (BATCH*HWN)  // 25088 rows

// GEMM tiling: 256x128 tile, 512 threads / 8 waves, 2-barrier glds structure
#define BM 256
#define BN 128
#define BK 32
#define NBM (MTOT/BM)       // 98
#define NBN (HIDN/BN)       // 6
#define NWG (NBM*NBN)       // 588 = 8*73 + 4 -> m204 bijective XCD swizzle
#define SWQ (NWG/8)         // 73
#define SWR (NWG%8)         // 4

// merged prep grid: first PWB blocks convert W, rest convert x->A
#define PWB (KN*HIDN/8/256) // 288
#define PAB (MTOT*48/256)   // 4704

typedef __attribute__((ext_vector_type(8))) short bf16x8;
typedef __attribute__((ext_vector_type(4))) float floatx4;

#define GP(p) ((const __attribute__((address_space(1))) void*)(p))
#define SP(p) ((__attribute__((address_space(3))) void*)(p))

static __device__ __forceinline__ short f2bf(float f) {
    __hip_bfloat16 h = __float2bfloat16(f);   // RNE
    return __builtin_bit_cast(short, h);
}

static __device__ __forceinline__ bf16x8 cvt8(const float* __restrict__ src) {
    float4 f0 = *(const float4*)(src);
    float4 f1 = *(const float4*)(src + 4);
    bf16x8 v;
    v[0]=f2bf(f0.x); v[1]=f2bf(f0.y); v[2]=f2bf(f0.z); v[3]=f2bf(f0.w);
    v[4]=f2bf(f1.x); v[5]=f2bf(f1.y); v[6]=f2bf(f1.z); v[7]=f2bf(f1.w);
    return v;
}

// ---------------------------------------------------------------------------
// prep: one launch. Blocks [0,288) convert W fp32->bf16 (73728 x8 elems).
// Blocks [288, 4992) build A in NATURAL patch order (no perm — the shuffle is
// applied at gemm staging): A[gr,k] = bf16(x[b,c,pixel]), gr = b*196+p,
// k = c*256+iy*16+ix. Reads sequential 64 B chunks, writes contiguous 32 B.
// ---------------------------------------------------------------------------
__global__ __launch_bounds__(256)
void prep(const float* __restrict__ x, const float* __restrict__ W,
          unsigned short* __restrict__ A, unsigned short* __restrict__ Wb)
{
    if (blockIdx.x < PWB) {
        const int idx = blockIdx.x * 256 + threadIdx.x;   // < 73728
        *(bf16x8*)(Wb + (size_t)idx * 8) = cvt8(W + (size_t)idx * 8);
        return;
    }
    const int idx = (blockIdx.x - PWB) * 256 + threadIdx.x;  // < 25088*48
    const int gr  = idx / 48;
    const int seg = idx - gr * 48;                    // 0..47
    const int b   = gr / HWN;
    const int p   = gr - b * HWN;                     // natural patch index
    const int py  = p / 14, px = p - py * 14;
    const int c   = seg >> 4;                         // 0..2
    const int iy  = seg & 15;                         // 0..15

    const float* src = x + (size_t)b * 3 * IMG2 + (size_t)c * IMG2
                         + (size_t)(py * 16 + iy) * IMGSZ + px * 16;
    bf16x8 v0 = cvt8(src);
    bf16x8 v1 = cvt8(src + 8);
    unsigned short* dst = A + (size_t)gr * KN + seg * 16;
    *(bf16x8*)(dst)     = v0;
    *(bf16x8*)(dst + 8) = v1;
}

// ---------------------------------------------------------------------------
// gemm: out[gr,n] = sum_k A[b*196 + perm[gr], k] * Wb[n,k] + bias[n]
// Round-5 verified 2-barrier glds structure, scaled to BM=256 / 512 threads:
//   * 3 glds/thread/iter (2 A-rows + 1 B-row, 16 B each) — same per-thread
//     staging cost as before, but 2x compute per barrier pair.
//   * grid = 588 blocks <= 768 co-resident (3/CU) -> single dispatch round,
//     no tail (1176-block config ran 1.53 rounds).
//   * m204 bijective XCD swizzle (588 % 8 != 0): consecutive lids share a
//     bm-panel on one XCD -> A panel fetched ~once into its L2.
// ---------------------------------------------------------------------------
__global__ __launch_bounds__(512, 6)
void gemm(const unsigned short* __restrict__ A, const int* __restrict__ perm,
          const unsigned short* __restrict__ Wb,
          const float* __restrict__ bias, float* __restrict__ out)
{
    __shared__ __align__(16) unsigned short As[BM * BK];  // 16 KB
    __shared__ __align__(16) unsigned short Bs[BN * BK];  // 8 KB

    const int tid = threadIdx.x;
    const int wg  = blockIdx.x;
    // m204 bijective swizzle: xcd<r get q+1 chunks, else q
    const int xcd  = wg & 7;
    const int slot = wg >> 3;
    const int base = (xcd < SWR) ? xcd * (SWQ + 1) : SWR * (SWQ + 1) + (xcd - SWR) * SWQ;
    const int lid  = base + slot;
    const int bm   = lid / NBN;
    const int bn   = lid - bm * NBN;

    // staging map: thread t stages 16 B of A-rows (t>>2) and (t>>2)+128 and
    // B-row (t>>2), k-seg (t&3). Dest = linear tid*16 B (glds constraint).
    const int srow = tid >> 2;             // 0..127
    const int sseg = tid & 3;
    const int gr0  = bm * BM + srow;       // output rows (perm-indexed source)
    const int gr1  = gr0 + 128;
    const int pr0  = (gr0 / HWN) * HWN + perm[gr0];
    const int pr1  = (gr1 / HWN) * HWN + perm[gr1];
    const unsigned short* ga0 = A  + (size_t)pr0 * KN + sseg * 8;
    const unsigned short* ga1 = A  + (size_t)pr1 * KN + sseg * 8;
    const unsigned short* gb  = Wb + (size_t)(bn * BN + srow) * KN + sseg * 8;

    // wave/fragment coords: 8 waves = 4 (M) x 2 (N), each owns 64x64
    const int lane = tid & 63;
    const int wave = tid >> 6;
    const int wm = (wave >> 1) * 64;
    const int wn = (wave & 1) * 64;
    const int lr = lane & 15;
    const int lq = lane >> 4;

    floatx4 acc[4][4] = {};

    for (int k0 = 0; k0 < KN; k0 += BK) {
        __builtin_amdgcn_global_load_lds(GP(ga0 + k0), SP(&As[tid * 8]),        16, 0, 0);
        __builtin_amdgcn_global_load_lds(GP(ga1 + k0), SP(&As[4096 + tid * 8]), 16, 0, 0);
        __builtin_amdgcn_global_load_lds(GP(gb  + k0), SP(&Bs[tid * 8]),        16, 0, 0);
        __syncthreads();

        bf16x8 bfrag[4];
        #pragma unroll
        for (int j = 0; j < 4; ++j)
            bfrag[j] = *(const bf16x8*)&Bs[(wn + j * 16 + lr) * BK + lq * 8];
        #pragma unroll
        for (int i = 0; i < 4; ++i) {
            bf16x8 afrag = *(const bf16x8*)&As[(wm + i * 16 + lr) * BK + lq * 8];
            #pragma unroll
            for (int j = 0; j < 4; ++j)
                acc[i][j] = __builtin_amdgcn_mfma_f32_16x16x32_bf16(
                                afrag, bfrag[j], acc[i][j], 0, 0, 0);
        }
        __syncthreads();
    }

    // epilogue: bias + contiguous store (C/D: col = lane&15, row = quad*4+reg)
    #pragma unroll
    for (int j = 0; j < 4; ++j) {
        const int gc = bn * BN + wn + j * 16 + lr;
        const float bv = bias[gc];
        #pragma unroll
        for (int i = 0; i < 4; ++i) {
            const int grow = bm * BM + wm + i * 16 + lq * 4;
            float* op = out + (size_t)grow * HIDN + gc;
            #pragma unroll
            for (int r = 0; r < 4; ++r)
                op[(size_t)r * HIDN] = acc[i][j][r] + bv;
        }
    }
}

extern "C" void kernel_launch(void* const* d_in, const int* in_sizes, int n_in,
                              void* d_out, int out_size, void* d_ws, size_t ws_size,
                              hipStream_t stream) {
    const float* x    = (const float*)d_in[0];
    const float* W    = (const float*)d_in[1];
    const float* bias = (const float*)d_in[2];
    const int*   perm = (const int*)d_in[3];
    float* out = (float*)d_out;

    // workspace: A bf16 [25088*768] (38.5 MB), Wb bf16 [768*768] (1.2 MB)
    unsigned short* A  = (unsigned short*)d_ws;
    unsigned short* Wb = A + (size_t)MTOT * KN;

    prep<<<dim3(PWB + PAB), dim3(256), 0, stream>>>(x, W, A, Wb);
    gemm<<<dim3(NWG), dim3(512), 0, stream>>>(A, perm, Wb, bias, out);
}

// Round 8
// 184.167 us; speedup vs baseline: 1.8900x; 1.8900x over previous
//
#include <hip/hip_runtime.h>
#include <hip/hip_bf16.h>

// Problem constants
#define BATCH  128
#define HWN    196          // (224/16)^2 patches per sample
#define HIDN   768
#define KN     768          // 3*16*16
#define IMGSZ  224
#define IMG2   (224*224)
#define MTOT   (BATCH*HWN)  // 25088 rows

// GEMM tiling: round-5 verified geometry (128x128, 256 thr, 3 blocks/CU),
// deepened to BK=64 (12 K-steps -> half the barrier/drain pairs).
#define BM 128
#define BN 128
#define BK 64
#define NT  (KN/BK)         // 12
#define NBM (MTOT/BM)       // 196
#define NBN (HIDN/BN)       // 6
#define NWG (NBM*NBN)       // 1176 = 8 * 147 -> bijective XCD swizzle
#define CPX (NWG/8)         // 147

// merged prep grid: first PWB blocks convert W, rest convert x->A (pairwise)
#define PWB   (KN*HIDN/8/256)   // 288
#define NPAIR (MTOT/2)          // 12544 patch pairs (px even, px+1)
#define PAB   (NPAIR*48/256)    // 2352

typedef __attribute__((ext_vector_type(8))) short bf16x8;
typedef __attribute__((ext_vector_type(4))) float floatx4;

#define GP(p) ((const __attribute__((address_space(1))) void*)(p))
#define SP(p) ((__attribute__((address_space(3))) void*)(p))

static __device__ __forceinline__ short f2bf(float f) {
    __hip_bfloat16 h = __float2bfloat16(f);   // RNE
    return __builtin_bit_cast(short, h);
}

static __device__ __forceinline__ bf16x8 cvt8(const float* __restrict__ src) {
    float4 f0 = *(const float4*)(src);
    float4 f1 = *(const float4*)(src + 4);
    bf16x8 v;
    v[0]=f2bf(f0.x); v[1]=f2bf(f0.y); v[2]=f2bf(f0.z); v[3]=f2bf(f0.w);
    v[4]=f2bf(f1.x); v[5]=f2bf(f1.y); v[6]=f2bf(f1.z); v[7]=f2bf(f1.w);
    return v;
}

// ---------------------------------------------------------------------------
// prep: one launch. Blocks [0,288): W fp32->bf16. Blocks [288,2640): build A
// in NATURAL patch order, TWO adjacent patches per thread (px even, px+1):
// the x read is one 128 B-aligned full cache line (32 consecutive floats =
// the same pixel-row of both patches), vs round-5's 64 B at 896 B stride.
// Writes: two contiguous 32 B streams (rows gr and gr+1), fully coalesced
// across consecutive seg threads. Perm is applied later at gemm staging.
// ---------------------------------------------------------------------------
__global__ __launch_bounds__(256)
void prep(const float* __restrict__ x, const float* __restrict__ W,
          unsigned short* __restrict__ A, unsigned short* __restrict__ Wb)
{
    if (blockIdx.x < PWB) {
        const int idx = blockIdx.x * 256 + threadIdx.x;   // < 73728
        *(bf16x8*)(Wb + (size_t)idx * 8) = cvt8(W + (size_t)idx * 8);
        return;
    }
    const int idx  = (blockIdx.x - PWB) * 256 + threadIdx.x;  // < 602112
    const int pi   = idx / 48;                 // pair index
    const int seg  = idx - pi * 48;            // 0..47  (c*16 + iy)
    const int gr   = pi * 2;                   // even global row
    const int b    = gr / HWN;
    const int p    = gr - b * HWN;             // even patch index
    const int py   = p / 14, px = p - py * 14; // px even -> 128B-aligned src
    const int c    = seg >> 4;                 // 0..2
    const int iy   = seg & 15;                 // 0..15

    const float* src = x + (size_t)b * 3 * IMG2 + (size_t)c * IMG2
                         + (size_t)(py * 16 + iy) * IMGSZ + px * 16;
    bf16x8 v0 = cvt8(src);        // patch p,   cols 0..7
    bf16x8 v1 = cvt8(src + 8);    // patch p,   cols 8..15
    bf16x8 v2 = cvt8(src + 16);   // patch p+1, cols 0..7
    bf16x8 v3 = cvt8(src + 24);   // patch p+1, cols 8..15
    unsigned short* d0 = A + (size_t)gr * KN + seg * 16;
    *(bf16x8*)(d0)          = v0;
    *(bf16x8*)(d0 + 8)      = v1;
    *(bf16x8*)(d0 + KN)     = v2;
    *(bf16x8*)(d0 + KN + 8) = v3;
}

// ---------------------------------------------------------------------------
// gemm: out[gr,n] = sum_k A[b*196 + perm[gr], k] * Wb[n,k] + bias[n]
// Round-5 verified 2-barrier glds structure with BK=64:
//   * 12 iterations -> half the vmcnt(0)-drain + barrier pairs of BK=32.
//   * LDS rows are 128 B -> 16 B-slot XOR swizzle, applied on the GLOBAL
//     source (xseg = (tid&7)^((tid>>3)&7); glds dest stays linear, rule #21)
//     and identically on the fragment reads (row&7 == lr&7).
//   * 8 glds/thread/iter (4 A + 4 B, 16 B each), wave-uniform scalar
//     per-instr/per-iter source advances.
//   * K-accumulation order identical to BK=32 (h=0 then h=1 per iter).
// ---------------------------------------------------------------------------
__global__ __launch_bounds__(256, 3)
void gemm(const unsigned short* __restrict__ A, const int* __restrict__ perm,
          const unsigned short* __restrict__ Wb,
          const float* __restrict__ bias, float* __restrict__ out)
{
    __shared__ __align__(16) unsigned short As[BM * BK];  // 16 KB
    __shared__ __align__(16) unsigned short Bs[BN * BK];  // 16 KB

    const int tid = threadIdx.x;
    const int wg  = blockIdx.x;
    const int lid = (wg & 7) * CPX + (wg >> 3);
    const int bm  = lid / NBN;
    const int bn  = lid - bm * NBN;

    // ---- staging map: glds instr g (g=0..3) covers rows g*32 + (tid>>3);
    // thread stages 16 B = 8 bf16 of k-unit (tid&7), source pre-XOR'd.
    const int trow = tid >> 3;                 // 0..31
    const int xseg = (tid & 7) ^ (trow & 7);   // source-side slot XOR
    // A pointers (perm-indexed output rows), one per glds instr
    const unsigned short* ga0; const unsigned short* ga1;
    const unsigned short* ga2; const unsigned short* ga3;
#define MKGA(PTR, G)                                                          \
    do {                                                                      \
        const int r  = bm * BM + (G) * 32 + trow;                             \
        const int pr = (r / HWN) * HWN + perm[r];                             \
        PTR = A + (size_t)pr * KN + xseg * 8;                                 \
    } while (0)
    MKGA(ga0, 0); MKGA(ga1, 1); MKGA(ga2, 2); MKGA(ga3, 3);
#undef MKGA
    const unsigned short* gb = Wb + (size_t)(bn * BN + trow) * KN + xseg * 8;

    // ---- fragment coords
    const int lane = tid & 63;
    const int wave = tid >> 6;
    const int wm = (wave >> 1) * 64;
    const int wn = (wave & 1) * 64;
    const int lr = lane & 15;
    const int lq = lane >> 4;
    const int rx = (lr & 7) << 4;              // read-side slot XOR (byte)
    const int rd0 = (lq * 16) ^ rx;            // k-half 0 byte offset in row
    const int rd1 = ((64 + lq * 16)) ^ rx;     // k-half 1

    floatx4 acc[4][4] = {};

    for (int it = 0; it < NT; ++it) {
        const int k0 = it * BK;
        __builtin_amdgcn_global_load_lds(GP(ga0 + k0),          SP(&As[tid * 8]),        16, 0, 0);
        __builtin_amdgcn_global_load_lds(GP(ga1 + k0),          SP(&As[2048 + tid * 8]), 16, 0, 0);
        __builtin_amdgcn_global_load_lds(GP(ga2 + k0),          SP(&As[4096 + tid * 8]), 16, 0, 0);
        __builtin_amdgcn_global_load_lds(GP(ga3 + k0),          SP(&As[6144 + tid * 8]), 16, 0, 0);
        __builtin_amdgcn_global_load_lds(GP(gb + k0),           SP(&Bs[tid * 8]),        16, 0, 0);
        __builtin_amdgcn_global_load_lds(GP(gb + 32 * KN + k0), SP(&Bs[2048 + tid * 8]), 16, 0, 0);
        __builtin_amdgcn_global_load_lds(GP(gb + 64 * KN + k0), SP(&Bs[4096 + tid * 8]), 16, 0, 0);
        __builtin_amdgcn_global_load_lds(GP(gb + 96 * KN + k0), SP(&Bs[6144 + tid * 8]), 16, 0, 0);
        __syncthreads();

        // k-half 0 (k0..k0+31)
        {
            bf16x8 bfrag[4];
            #pragma unroll
            for (int j = 0; j < 4; ++j)
                bfrag[j] = *(const bf16x8*)((const char*)Bs + (wn + j * 16 + lr) * 128 + rd0);
            #pragma unroll
            for (int i = 0; i < 4; ++i) {
                const bf16x8 afrag = *(const bf16x8*)((const char*)As + (wm + i * 16 + lr) * 128 + rd0);
                #pragma unroll
                for (int j = 0; j < 4; ++j)
                    acc[i][j] = __builtin_amdgcn_mfma_f32_16x16x32_bf16(
                                    afrag, bfrag[j], acc[i][j], 0, 0, 0);
            }
        }
        // k-half 1 (k0+32..k0+63)
        {
            bf16x8 bfrag[4];
            #pragma unroll
            for (int j = 0; j < 4; ++j)
                bfrag[j] = *(const bf16x8*)((const char*)Bs + (wn + j * 16 + lr) * 128 + rd1);
            #pragma unroll
            for (int i = 0; i < 4; ++i) {
                const bf16x8 afrag = *(const bf16x8*)((const char*)As + (wm + i * 16 + lr) * 128 + rd1);
                #pragma unroll
                for (int j = 0; j < 4; ++j)
                    acc[i][j] = __builtin_amdgcn_mfma_f32_16x16x32_bf16(
                                    afrag, bfrag[j], acc[i][j], 0, 0, 0);
            }
        }
        __syncthreads();
    }

    // epilogue: bias + contiguous store (C/D: col = lane&15, row = quad*4+reg)
    #pragma unroll
    for (int j = 0; j < 4; ++j) {
        const int gc = bn * BN + wn + j * 16 + lr;
        const float bv = bias[gc];
        #pragma unroll
        for (int i = 0; i < 4; ++i) {
            const int grow = bm * BM + wm + i * 16 + lq * 4;
            float* op = out + (size_t)grow * HIDN + gc;
            #pragma unroll
            for (int r = 0; r < 4; ++r)
                op[(size_t)r * HIDN] = acc[i][j][r] + bv;
        }
    }
}

extern "C" void kernel_launch(void* const* d_in, const int* in_sizes, int n_in,
                              void* d_out, int out_size, void* d_ws, size_t ws_size,
                              hipStream_t stream) {
    const float* x    = (const float*)d_in[0];
    const float* W    = (const float*)d_in[1];
    const float* bias = (const float*)d_in[2];
    const int*   perm = (const int*)d_in[3];
    float* out = (float*)d_out;

    // workspace: A bf16 [25088*768] (38.5 MB), Wb bf16 [768*768] (1.2 MB)
    unsigned short* A  = (unsigned short*)d_ws;
    unsigned short* Wb = A + (size_t)MTOT * KN;

    prep<<<dim3(PWB + PAB), dim3(256), 0, stream>>>(x, W, A, Wb);
    gemm<<<dim3(NWG), dim3(256), 0, stream>>>(A, perm, Wb, bias, out);
}

// Round 9
// 173.713 us; speedup vs baseline: 2.0038x; 1.0602x over previous
//
#include <hip/hip_runtime.h>
#include <hip/hip_bf16.h>

// Problem constants
#define BATCH  128
#define HWN    196          // (224/16)^2 patches per sample
#define HIDN   768
#define KN     768          // 3*16*16
#define IMGSZ  224
#define IMG2   (224*224)
#define MTOT   (BATCH*HWN)  // 25088 rows

// GEMM tiling: 128x128, 256 thr, BK=64 (round-8 verified, conflicts=0),
// now LDS double-buffered with counted-vmcnt staging (T4).
#define BM 128
#define BN 128
#define BK 64
#define NT  (KN/BK)         // 12
#define NBM (MTOT/BM)       // 196
#define NBN (HIDN/BN)       // 6
#define NWG (NBM*NBN)       // 1176 = 8 * 147 -> bijective XCD swizzle
#define CPX (NWG/8)         // 147

// merged prep grid: first PWB blocks convert W, rest convert x->A
#define PWB (KN*HIDN/8/256)  // 288
#define PAB (MTOT*48/256)    // 4704

typedef __attribute__((ext_vector_type(8))) short bf16x8;
typedef __attribute__((ext_vector_type(4))) float floatx4;

#define GP(p) ((const __attribute__((address_space(1))) void*)(p))
#define SP(p) ((__attribute__((address_space(3))) void*)(p))

static __device__ __forceinline__ short f2bf(float f) {
    __hip_bfloat16 h = __float2bfloat16(f);   // RNE
    return __builtin_bit_cast(short, h);
}

static __device__ __forceinline__ bf16x8 cvt8(const float* __restrict__ src) {
    float4 f0 = *(const float4*)(src);
    float4 f1 = *(const float4*)(src + 4);
    bf16x8 v;
    v[0]=f2bf(f0.x); v[1]=f2bf(f0.y); v[2]=f2bf(f0.z); v[3]=f2bf(f0.w);
    v[4]=f2bf(f1.x); v[5]=f2bf(f1.y); v[6]=f2bf(f1.z); v[7]=f2bf(f1.w);
    return v;
}

// ---------------------------------------------------------------------------
// prep: one launch. Blocks [0,288): W fp32->bf16. Blocks [288,4992): build A
// in NATURAL patch order (round-5 per-patch form — the round-8 pair variant
// regressed ~6us). A[gr,k] = bf16(x[b,c,pixel]); one thread = one (c,iy)
// 16-float segment: 64 B read, contiguous 32 B write. Perm applied at gemm.
// ---------------------------------------------------------------------------
__global__ __launch_bounds__(256)
void prep(const float* __restrict__ x, const float* __restrict__ W,
          unsigned short* __restrict__ A, unsigned short* __restrict__ Wb)
{
    if (blockIdx.x < PWB) {
        const int idx = blockIdx.x * 256 + threadIdx.x;   // < 73728
        *(bf16x8*)(Wb + (size_t)idx * 8) = cvt8(W + (size_t)idx * 8);
        return;
    }
    const int idx = (blockIdx.x - PWB) * 256 + threadIdx.x;  // < 25088*48
    const int gr  = idx / 48;
    const int seg = idx - gr * 48;                    // 0..47
    const int b   = gr / HWN;
    const int p   = gr - b * HWN;                     // natural patch index
    const int py  = p / 14, px = p - py * 14;
    const int c   = seg >> 4;                         // 0..2
    const int iy  = seg & 15;                         // 0..15

    const float* src = x + (size_t)b * 3 * IMG2 + (size_t)c * IMG2
                         + (size_t)(py * 16 + iy) * IMGSZ + px * 16;
    bf16x8 v0 = cvt8(src);
    bf16x8 v1 = cvt8(src + 8);
    unsigned short* dst = A + (size_t)gr * KN + seg * 16;
    *(bf16x8*)(dst)     = v0;
    *(bf16x8*)(dst + 8) = v1;
}

// ---------------------------------------------------------------------------
// gemm: out[gr,n] = sum_k A[b*196 + perm[gr], k] * Wb[n,k] + bias[n]
// Round-8 verified BK=64 swizzled structure + T4 counted-vmcnt dbuf:
//   * LDS double-buffered (2 x (16+16) KB = 64 KB). Per iter: issue tile
//     t+1's 8 glds into buf^1, s_waitcnt vmcnt(8) (tile t landed, t+1's 8
//     STAY IN FLIGHT across the barrier — never vmcnt(0) in the loop),
//     raw s_barrier, compute buf, trailing s_barrier (protects buf from
//     t+2's glds while laggard waves still read it).
//   * raw barriers + inline-asm vmcnt, NOT __syncthreads (which re-inserts
//     the vmcnt(0) drain); sched_barrier(0) pins ds_reads behind the wait.
//   * source-side slot XOR (xseg) + read-side XOR -> bank conflicts = 0
//     (verified round 8). Buffer indices are macro literals (rule #20).
//   * K-accumulation order identical -> bit-identical numerics.
// ---------------------------------------------------------------------------
__global__ __launch_bounds__(256, 3)
void gemm(const unsigned short* __restrict__ A, const int* __restrict__ perm,
          const unsigned short* __restrict__ Wb,
          const float* __restrict__ bias, float* __restrict__ out)
{
    __shared__ __align__(16) unsigned short As[2][BM * BK];  // 2 x 16 KB
    __shared__ __align__(16) unsigned short Bs[2][BN * BK];  // 2 x 16 KB

    const int tid = threadIdx.x;
    const int wg  = blockIdx.x;
    const int lid = (wg & 7) * CPX + (wg >> 3);
    const int bm  = lid / NBN;
    const int bn  = lid - bm * NBN;

    // ---- staging map: glds instr g covers rows g*32 + (tid>>3);
    // thread stages 16 B of k-unit (tid&7), source pre-XOR'd.
    const int trow = tid >> 3;                 // 0..31
    const int xseg = (tid & 7) ^ (trow & 7);   // source-side slot XOR
    const unsigned short* ga0; const unsigned short* ga1;
    const unsigned short* ga2; const unsigned short* ga3;
#define MKGA(PTR, G)                                                          \
    do {                                                                      \
        const int r  = bm * BM + (G) * 32 + trow;                             \
        const int pr = (r / HWN) * HWN + perm[r];                             \
        PTR = A + (size_t)pr * KN + xseg * 8;                                 \
    } while (0)
    MKGA(ga0, 0); MKGA(ga1, 1); MKGA(ga2, 2); MKGA(ga3, 3);
#undef MKGA
    const unsigned short* gb = Wb + (size_t)(bn * BN + trow) * KN + xseg * 8;

    // ---- fragment coords
    const int lane = tid & 63;
    const int wave = tid >> 6;
    const int wm = (wave >> 1) * 64;
    const int wn = (wave & 1) * 64;
    const int lr = lane & 15;
    const int lq = lane >> 4;
    const int rx  = (lr & 7) << 4;             // read-side slot XOR (byte)
    const int rd0 = (lq * 16) ^ rx;            // k-half 0 byte offset in row
    const int rd1 = (64 + lq * 16) ^ rx;       // k-half 1

    floatx4 acc[4][4] = {};

#define STAGE(BUF, K0)                                                        \
    do {                                                                      \
        __builtin_amdgcn_global_load_lds(GP(ga0 + (K0)),          SP(&As[BUF][tid * 8]),        16, 0, 0); \
        __builtin_amdgcn_global_load_lds(GP(ga1 + (K0)),          SP(&As[BUF][2048 + tid * 8]), 16, 0, 0); \
        __builtin_amdgcn_global_load_lds(GP(ga2 + (K0)),          SP(&As[BUF][4096 + tid * 8]), 16, 0, 0); \
        __builtin_amdgcn_global_load_lds(GP(ga3 + (K0)),          SP(&As[BUF][6144 + tid * 8]), 16, 0, 0); \
        __builtin_amdgcn_global_load_lds(GP(gb + (K0)),           SP(&Bs[BUF][tid * 8]),        16, 0, 0); \
        __builtin_amdgcn_global_load_lds(GP(gb + 32 * KN + (K0)), SP(&Bs[BUF][2048 + tid * 8]), 16, 0, 0); \
        __builtin_amdgcn_global_load_lds(GP(gb + 64 * KN + (K0)), SP(&Bs[BUF][4096 + tid * 8]), 16, 0, 0); \
        __builtin_amdgcn_global_load_lds(GP(gb + 96 * KN + (K0)), SP(&Bs[BUF][6144 + tid * 8]), 16, 0, 0); \
    } while (0)

#define COMPHALF(BUF, RD)                                                     \
    do {                                                                      \
        bf16x8 bfrag[4];                                                      \
        _Pragma("unroll")                                                     \
        for (int j = 0; j < 4; ++j)                                           \
            bfrag[j] = *(const bf16x8*)((const char*)Bs[BUF] + (wn + j * 16 + lr) * 128 + (RD)); \
        _Pragma("unroll")                                                     \
        for (int i = 0; i < 4; ++i) {                                         \
            const bf16x8 afrag = *(const bf16x8*)((const char*)As[BUF] + (wm + i * 16 + lr) * 128 + (RD)); \
            _Pragma("unroll")                                                 \
            for (int j = 0; j < 4; ++j)                                       \
                acc[i][j] = __builtin_amdgcn_mfma_f32_16x16x32_bf16(          \
                                afrag, bfrag[j], acc[i][j], 0, 0, 0);         \
        }                                                                     \
    } while (0)

    // STEP: PF=1 -> stage next tile, counted wait; PF=0 (last) -> drain.
#define STEP(T, CUR, NXT, PF)                                                 \
    do {                                                                      \
        if (PF) STAGE(NXT, ((T) + 1) * BK);                                   \
        if (PF) asm volatile("s_waitcnt vmcnt(8)" ::: "memory");              \
        else    asm volatile("s_waitcnt vmcnt(0)" ::: "memory");              \
        __builtin_amdgcn_s_barrier();                                         \
        __builtin_amdgcn_sched_barrier(0);                                    \
        COMPHALF(CUR, rd0);                                                   \
        COMPHALF(CUR, rd1);                                                   \
        if (PF) {                                                             \
            __builtin_amdgcn_sched_barrier(0);                                \
            __builtin_amdgcn_s_barrier();  /* all reads of CUR done */        \
        }                                                                     \
    } while (0)

    // prologue: stage tile 0 into buf 0
    STAGE(0, 0);

    for (int tt = 0; tt < NT - 2; tt += 2) {      // steps 0..9
        STEP(tt,     0, 1, 1);
        STEP(tt + 1, 1, 0, 1);
    }
    STEP(NT - 2, 0, 1, 1);                        // step 10
    STEP(NT - 1, 1, 0, 0);                        // step 11 (no prefetch)

#undef STEP
#undef COMPHALF
#undef STAGE

    // epilogue: bias + contiguous store (C/D: col = lane&15, row = quad*4+reg)
    #pragma unroll
    for (int j = 0; j < 4; ++j) {
        const int gc = bn * BN + wn + j * 16 + lr;
        const float bv = bias[gc];
        #pragma unroll
        for (int i = 0; i < 4; ++i) {
            const int grow = bm * BM + wm + i * 16 + lq * 4;
            float* op = out + (size_t)grow * HIDN + gc;
            #pragma unroll
            for (int r = 0; r < 4; ++r)
                op[(size_t)r * HIDN] = acc[i][j][r] + bv;
        }
    }
}

extern "C" void kernel_launch(void* const* d_in, const int* in_sizes, int n_in,
                              void* d_out, int out_size, void* d_ws, size_t ws_size,
                              hipStream_t stream) {
    const float* x    = (const float*)d_in[0];
    const float* W    = (const float*)d_in[1];
    const float* bias = (const float*)d_in[2];
    const int*   perm = (const int*)d_in[3];
    float* out = (float*)d_out;

    // workspace: A bf16 [25088*768] (38.5 MB), Wb bf16 [768*768] (1.2 MB)
    unsigned short* A  = (unsigned short*)d_ws;
    unsigned short* Wb = A + (size_t)MTOT * KN;

    prep<<<dim3(PWB + PAB), dim3(256), 0, stream>>>(x, W, A, Wb);
    gemm<<<dim3(NWG), dim3(256), 0, stream>>>(A, perm, Wb, bias, out);
}

// Round 10
// 173.095 us; speedup vs baseline: 2.0109x; 1.0036x over previous
//
#include <hip/hip_runtime.h>
#include <hip/hip_bf16.h>

// Problem constants
#define BATCH  128
#define HWN    196          // (224/16)^2 patches per sample
#define HIDN   768
#define KN     768          // 3*16*16
#define IMGSZ  224
#define IMG2   (224*224)
#define MTOT   (BATCH*HWN)  // 25088 rows

// GEMM tiling: 128x128, 256 thr, BK=64, A double-buffered + B single-buffered
// (B is L2-resident Wb), counted-vmcnt staging. LDS 48 KB -> 3 blocks/CU.
#define BM 128
#define BN 128
#define BK 64
#define NT  (KN/BK)         // 12
#define NBM (MTOT/BM)       // 196
#define NBN (HIDN/BN)       // 6
#define NWG (NBM*NBN)       // 1176 = 8 * 147 -> bijective XCD swizzle
#define CPX (NWG/8)         // 147

// merged prep grid: first PWB blocks convert W, rest convert x->A
#define PWB (KN*HIDN/8/256)  // 288
#define PAB (MTOT*48/256)    // 4704

typedef __attribute__((ext_vector_type(8))) short bf16x8;
typedef __attribute__((ext_vector_type(4))) float floatx4;

#define GP(p) ((const __attribute__((address_space(1))) void*)(p))
#define SP(p) ((__attribute__((address_space(3))) void*)(p))

static __device__ __forceinline__ short f2bf(float f) {
    __hip_bfloat16 h = __float2bfloat16(f);   // RNE
    return __builtin_bit_cast(short, h);
}

static __device__ __forceinline__ bf16x8 cvt8(const float* __restrict__ src) {
    float4 f0 = *(const float4*)(src);
    float4 f1 = *(const float4*)(src + 4);
    bf16x8 v;
    v[0]=f2bf(f0.x); v[1]=f2bf(f0.y); v[2]=f2bf(f0.z); v[3]=f2bf(f0.w);
    v[4]=f2bf(f1.x); v[5]=f2bf(f1.y); v[6]=f2bf(f1.z); v[7]=f2bf(f1.w);
    return v;
}

// ---------------------------------------------------------------------------
// prep (unchanged round-9): blocks [0,288): W fp32->bf16; [288,4992): A in
// NATURAL patch order. One thread = one (c,iy) 16-float segment: 64 B read,
// contiguous 32 B write. Perm applied at gemm staging.
// ---------------------------------------------------------------------------
__global__ __launch_bounds__(256)
void prep(const float* __restrict__ x, const float* __restrict__ W,
          unsigned short* __restrict__ A, unsigned short* __restrict__ Wb)
{
    if (blockIdx.x < PWB) {
        const int idx = blockIdx.x * 256 + threadIdx.x;   // < 73728
        *(bf16x8*)(Wb + (size_t)idx * 8) = cvt8(W + (size_t)idx * 8);
        return;
    }
    const int idx = (blockIdx.x - PWB) * 256 + threadIdx.x;  // < 25088*48
    const int gr  = idx / 48;
    const int seg = idx - gr * 48;                    // 0..47
    const int b   = gr / HWN;
    const int p   = gr - b * HWN;                     // natural patch index
    const int py  = p / 14, px = p - py * 14;
    const int c   = seg >> 4;                         // 0..2
    const int iy  = seg & 15;                         // 0..15

    const float* src = x + (size_t)b * 3 * IMG2 + (size_t)c * IMG2
                         + (size_t)(py * 16 + iy) * IMGSZ + px * 16;
    bf16x8 v0 = cvt8(src);
    bf16x8 v1 = cvt8(src + 8);
    unsigned short* dst = A + (size_t)gr * KN + seg * 16;
    *(bf16x8*)(dst)     = v0;
    *(bf16x8*)(dst + 8) = v1;
}

// ---------------------------------------------------------------------------
// gemm: out[gr,n] = sum_k A[b*196 + perm[gr], k] * Wb[n,k] + bias[n]
// Round-9 counted-vmcnt structure, refined:
//   * As double-buffered (2x16 KB), Bs SINGLE (16 KB): Wb is L2-resident
//     (6 distinct panels / 1176 blocks), so B(t) staged and consumed in the
//     same step costs only ~L2 latency; A(t+1) keeps full-step HBM cover.
//     LDS 48 KB -> 3 blocks/CU (was 64 KB -> 2).
//   * Per step: issue B(t) 4 glds, A(t+1) 4 glds; s_waitcnt vmcnt(4)
//     [queue: A(t)4 | B(t)4 | A(t+1)4 -> retires A(t)+B(t), A(t+1) stays
//     in flight across the barrier]; s_barrier; MFMA; s_barrier.
//   * T5: s_setprio(1) around the MFMA cluster (role-split schedule).
//   * source-side slot XOR + read-side XOR: bank conflicts = 0 (r8-verified).
//   * Same K-accumulation order -> bit-identical numerics.
// Hazards: trailing barrier of step t-1 guards Bs AND As[NXT] overwrites
// (all waves finished compute before any wave issues step t's glds).
// ---------------------------------------------------------------------------
__global__ __launch_bounds__(256, 3)
void gemm(const unsigned short* __restrict__ A, const int* __restrict__ perm,
          const unsigned short* __restrict__ Wb,
          const float* __restrict__ bias, float* __restrict__ out)
{
    __shared__ __align__(16) unsigned short As[2][BM * BK];  // 2 x 16 KB
    __shared__ __align__(16) unsigned short Bs[BN * BK];     // 16 KB

    const int tid = threadIdx.x;
    const int wg  = blockIdx.x;
    const int lid = (wg & 7) * CPX + (wg >> 3);
    const int bm  = lid / NBN;
    const int bn  = lid - bm * NBN;

    // ---- staging map: glds instr g covers rows g*32 + (tid>>3);
    // thread stages 16 B of k-unit (tid&7), source pre-XOR'd.
    const int trow = tid >> 3;                 // 0..31
    const int xseg = (tid & 7) ^ (trow & 7);   // source-side slot XOR
    const unsigned short* ga0; const unsigned short* ga1;
    const unsigned short* ga2; const unsigned short* ga3;
#define MKGA(PTR, G)                                                          \
    do {                                                                      \
        const int r  = bm * BM + (G) * 32 + trow;                             \
        const int pr = (r / HWN) * HWN + perm[r];                             \
        PTR = A + (size_t)pr * KN + xseg * 8;                                 \
    } while (0)
    MKGA(ga0, 0); MKGA(ga1, 1); MKGA(ga2, 2); MKGA(ga3, 3);
#undef MKGA
    const unsigned short* gb = Wb + (size_t)(bn * BN + trow) * KN + xseg * 8;

    // ---- fragment coords
    const int lane = tid & 63;
    const int wave = tid >> 6;
    const int wm = (wave >> 1) * 64;
    const int wn = (wave & 1) * 64;
    const int lr = lane & 15;
    const int lq = lane >> 4;
    const int rx  = (lr & 7) << 4;             // read-side slot XOR (byte)
    const int rd0 = (lq * 16) ^ rx;            // k-half 0 byte offset in row
    const int rd1 = (64 + lq * 16) ^ rx;       // k-half 1

    floatx4 acc[4][4] = {};

#define STAGE_B(K0)                                                           \
    do {                                                                      \
        __builtin_amdgcn_global_load_lds(GP(gb + (K0)),           SP(&Bs[tid * 8]),        16, 0, 0); \
        __builtin_amdgcn_global_load_lds(GP(gb + 32 * KN + (K0)), SP(&Bs[2048 + tid * 8]), 16, 0, 0); \
        __builtin_amdgcn_global_load_lds(GP(gb + 64 * KN + (K0)), SP(&Bs[4096 + tid * 8]), 16, 0, 0); \
        __builtin_amdgcn_global_load_lds(GP(gb + 96 * KN + (K0)), SP(&Bs[6144 + tid * 8]), 16, 0, 0); \
    } while (0)

#define STAGE_A(BUF, K0)                                                      \
    do {                                                                      \
        __builtin_amdgcn_global_load_lds(GP(ga0 + (K0)), SP(&As[BUF][tid * 8]),        16, 0, 0); \
        __builtin_amdgcn_global_load_lds(GP(ga1 + (K0)), SP(&As[BUF][2048 + tid * 8]), 16, 0, 0); \
        __builtin_amdgcn_global_load_lds(GP(ga2 + (K0)), SP(&As[BUF][4096 + tid * 8]), 16, 0, 0); \
        __builtin_amdgcn_global_load_lds(GP(ga3 + (K0)), SP(&As[BUF][6144 + tid * 8]), 16, 0, 0); \
    } while (0)

#define COMPHALF(BUF, RD)                                                     \
    do {                                                                      \
        bf16x8 bfrag[4];                                                      \
        _Pragma("unroll")                                                     \
        for (int j = 0; j < 4; ++j)                                           \
            bfrag[j] = *(const bf16x8*)((const char*)Bs + (wn + j * 16 + lr) * 128 + (RD)); \
        _Pragma("unroll")                                                     \
        for (int i = 0; i < 4; ++i) {                                         \
            const bf16x8 afrag = *(const bf16x8*)((const char*)As[BUF] + (wm + i * 16 + lr) * 128 + (RD)); \
            _Pragma("unroll")                                                 \
            for (int j = 0; j < 4; ++j)                                       \
                acc[i][j] = __builtin_amdgcn_mfma_f32_16x16x32_bf16(          \
                                afrag, bfrag[j], acc[i][j], 0, 0, 0);         \
        }                                                                     \
    } while (0)

    // STEP: PF=1 -> prefetch A(t+1), counted wait; PF=0 (last) -> drain.
#define STEP(T, CUR, NXT, PF)                                                 \
    do {                                                                      \
        STAGE_B((T) * BK);                                                    \
        if (PF) STAGE_A(NXT, ((T) + 1) * BK);                                 \
        if (PF) asm volatile("s_waitcnt vmcnt(4)" ::: "memory");              \
        else    asm volatile("s_waitcnt vmcnt(0)" ::: "memory");              \
        __builtin_amdgcn_s_barrier();                                         \
        __builtin_amdgcn_sched_barrier(0);                                    \
        __builtin_amdgcn_s_setprio(1);                                        \
        COMPHALF(CUR, rd0);                                                   \
        COMPHALF(CUR, rd1);                                                   \
        __builtin_amdgcn_s_setprio(0);                                        \
        if (PF) {                                                             \
            __builtin_amdgcn_sched_barrier(0);                                \
            __builtin_amdgcn_s_barrier();  /* all reads of As[CUR]+Bs done */ \
        }                                                                     \
    } while (0)

    // prologue: stage A tile 0 into buf 0 (queue = A(0)x4)
    STAGE_A(0, 0);

    for (int tt = 0; tt < NT - 2; tt += 2) {      // steps 0..9
        STEP(tt,     0, 1, 1);
        STEP(tt + 1, 1, 0, 1);
    }
    STEP(NT - 2, 0, 1, 1);                        // step 10
    STEP(NT - 1, 1, 0, 0);                        // step 11 (no prefetch)

#undef STEP
#undef COMPHALF
#undef STAGE_A
#undef STAGE_B

    // epilogue: bias + contiguous store (C/D: col = lane&15, row = quad*4+reg)
    #pragma unroll
    for (int j = 0; j < 4; ++j) {
        const int gc = bn * BN + wn + j * 16 + lr;
        const float bv = bias[gc];
        #pragma unroll
        for (int i = 0; i < 4; ++i) {
            const int grow = bm * BM + wm + i * 16 + lq * 4;
            float* op = out + (size_t)grow * HIDN + gc;
            #pragma unroll
            for (int r = 0; r < 4; ++r)
                op[(size_t)r * HIDN] = acc[i][j][r] + bv;
        }
    }
}

extern "C" void kernel_launch(void* const* d_in, const int* in_sizes, int n_in,
                              void* d_out, int out_size, void* d_ws, size_t ws_size,
                              hipStream_t stream) {
    const float* x    = (const float*)d_in[0];
    const float* W    = (const float*)d_in[1];
    const float* bias = (const float*)d_in[2];
    const int*   perm = (const int*)d_in[3];
    float* out = (float*)d_out;

    // workspace: A bf16 [25088*768] (38.5 MB), Wb bf16 [768*768] (1.2 MB)
    unsigned short* A  = (unsigned short*)d_ws;
    unsigned short* Wb = A + (size_t)MTOT * KN;

    prep<<<dim3(PWB + PAB), dim3(256), 0, stream>>>(x, W, A, Wb);
    gemm<<<dim3(NWG), dim3(256), 0, stream>>>(A, perm, Wb, bias, out);
}